// Round 17
// baseline (307.647 us; speedup 1.0000x reference)
//
#include <hip/hip_runtime.h>
#include <cmath>

#define FACTOR 0.08838834764831845f

typedef short s16x8 __attribute__((ext_vector_type(8)));
typedef float f32x4 __attribute__((ext_vector_type(4)));
typedef float f32x16 __attribute__((ext_vector_type(16)));
typedef unsigned int u32;

__device__ __forceinline__ unsigned short f2bf(float x) {
  unsigned int u = __float_as_uint(x);
  u += 0x7FFFu + ((u >> 16) & 1u);
  return (unsigned short)(u >> 16);
}

__device__ __forceinline__ s16x8 pack8(float4 a, float4 b) {
  s16x8 r;
  r[0] = (short)f2bf(a.x); r[1] = (short)f2bf(a.y);
  r[2] = (short)f2bf(a.z); r[3] = (short)f2bf(a.w);
  r[4] = (short)f2bf(b.x); r[5] = (short)f2bf(b.y);
  r[6] = (short)f2bf(b.z); r[7] = (short)f2bf(b.w);
  return r;
}

__device__ __forceinline__ void gload_lds16(const void* g, void* l) {
  __builtin_amdgcn_global_load_lds(
      (const __attribute__((address_space(1))) u32*)g,
      (__attribute__((address_space(3))) u32*)l, 16, 0, 0);
}

// ---------------------------------------------------------------------------
// f32 -> bf16 convert, 8 elems/thread (n must be a multiple of 2048)
// ---------------------------------------------------------------------------
__global__ __launch_bounds__(256) void cvt_bf16(
    const float* __restrict__ src, unsigned short* __restrict__ dst, int n)
{
  const int i = (blockIdx.x * 256 + threadIdx.x) * 8;
  if (i < n) {
    const float4 a = *(const float4*)(src + i);
    const float4 b = *(const float4*)(src + i + 4);
    *(s16x8*)&dst[i] = pack8(a, b);
  }
}

// ---------------------------------------------------------------------------
// bf16 MFMA GEMM: C = A[M,K] @ B[N,K]^T (+bias). DMA-staged (global_load_lds)
// into ko-slab LDS (8 slabs x 2080B, 32B pad -> conflict-free b128 frags).
// m97-style single-buffer loop. 128x128 tile, 4 waves (2x2), BK=64.
// mode 0: f32 C | mode 3: bf16 C | mode 4/5: Vt scatters (5 = fused V remap)
// ---------------------------------------------------------------------------
__global__ __launch_bounds__(256) void gemm_bf(
    const unsigned short* __restrict__ A, const unsigned short* __restrict__ B,
    const float* __restrict__ bias, void* __restrict__ C,
    int M, int N, int K, int mode)
{
  __shared__ unsigned short ASl[8 * 1040];   // slab ko: [row 128][8 bf16] + 16 pad
  __shared__ unsigned short BSl[8 * 1040];

  const int tid = threadIdx.x;
  const int w = tid >> 6, lane = tid & 63;
  const int l16 = lane & 15, lg = lane >> 4;
  const int wm = w >> 1, wn = w & 1;
  const int m0 = blockIdx.x * 128;
  const int n0 = blockIdx.y * 128;

  f32x4 acc[4][4];
#pragma unroll
  for (int mt = 0; mt < 4; ++mt)
#pragma unroll
    for (int nt = 0; nt < 4; ++nt)
#pragma unroll
      for (int r = 0; r < 4; ++r) acc[mt][nt][r] = 0.f;

#pragma unroll 1
  for (int k0 = 0; k0 < K; k0 += 64) {
    __builtin_amdgcn_s_barrier();            // readers of prior slab done
#pragma unroll
    for (int i = 0; i < 4; ++i) {
      const int u = i * 256 + tid;           // unit: ko-major, 16B each
      const int row = u & 127, ko = u >> 7;
      const int dst = ko * 1040 + row * 8;   // shorts
      gload_lds16(A + (size_t)(m0 + row) * K + k0 + ko * 8, &ASl[dst]);
      const unsigned short* bp;
      if (mode == 5) {
        const int t = n0 + row;
        const int q3 = t >> 10, n = t & 1023;
        const int bb = q3 / 3, cd = q3 - 3 * bb;
        bp = B + (((size_t)(bb * 1024 + n)) * 3 + cd) * 512 + k0 + ko * 8;
      } else {
        bp = B + (size_t)(n0 + row) * K + k0 + ko * 8;
      }
      gload_lds16(bp, &BSl[dst]);
    }
    asm volatile("s_waitcnt vmcnt(0)" ::: "memory");  // own DMAs landed
    __builtin_amdgcn_s_barrier();                     // all waves' DMAs landed

#pragma unroll
    for (int ks = 0; ks < 2; ++ks) {
      s16x8 af[4], bf[4];
#pragma unroll
      for (int mt = 0; mt < 4; ++mt)
        af[mt] = *(const s16x8*)&ASl[(ks * 4 + lg) * 1040 + (wm * 64 + mt * 16 + l16) * 8];
#pragma unroll
      for (int nt = 0; nt < 4; ++nt)
        bf[nt] = *(const s16x8*)&BSl[(ks * 4 + lg) * 1040 + (wn * 64 + nt * 16 + l16) * 8];
#pragma unroll
      for (int mt = 0; mt < 4; ++mt)
#pragma unroll
        for (int nt = 0; nt < 4; ++nt)
          acc[mt][nt] = __builtin_amdgcn_mfma_f32_16x16x32_bf16(af[mt], bf[nt], acc[mt][nt], 0, 0, 0);
    }
  }

  const int rbase = m0 + wm * 64;
  const int cbase = n0 + wn * 64;

  if (mode == 0 || mode == 3) {
#pragma unroll
    for (int nt = 0; nt < 4; ++nt) {
      const int c = cbase + nt * 16 + l16;
      const float bb = bias ? bias[c] : 0.f;
#pragma unroll
      for (int mt = 0; mt < 4; ++mt) {
#pragma unroll
        for (int r = 0; r < 4; ++r) {
          const int row = rbase + mt * 16 + lg * 4 + r;
          const float v = acc[mt][nt][r] + bb;
          if (mode == 0) ((float*)C)[(size_t)row * N + c] = v;
          else           ((unsigned short*)C)[(size_t)row * N + c] = f2bf(v);
        }
      }
    }
  } else {
    unsigned short* Cb = (unsigned short*)C;
#pragma unroll
    for (int mt = 0; mt < 4; ++mt) {
#pragma unroll
      for (int r = 0; r < 4; ++r) {
        const int ch = rbase + mt * 16 + lg * 4 + r;
        const float bb = bias ? bias[ch] : 0.f;
        const int h = ch >> 5, dq = ch & 31;
#pragma unroll
        for (int nt = 0; nt < 4; ++nt) {
          const int t = cbase + nt * 16 + l16;
          size_t off;
          if (mode == 4) {
            const int b = t >> 10, n = t & 1023;
            off = (((size_t)(b * 16 + h)) * 128 + dq) * 1024 + n;
          } else {
            const int q3 = t >> 10, n = t & 1023;
            const int b = q3 / 3, cd = q3 - 3 * b;
            off = (((size_t)(b * 16 + h)) * 128 + 32 + cd * 32 + dq) * 1024 + n;
          }
          Cb[off] = f2bf(acc[mt][nt][r] + bb);
        }
      }
    }
  }
}

// ---------------------------------------------------------------------------
// Flash attention (R16-passing structure). Only change: Hres/Vres now bf16.
// ---------------------------------------------------------------------------
__global__ __launch_bounds__(256, 2) void attn_mfma(
    const unsigned short* __restrict__ Qg, const unsigned short* __restrict__ Kg,
    const unsigned short* __restrict__ Vtg, const float* __restrict__ rbf,
    const float* __restrict__ Dm, const int* __restrict__ msk,
    unsigned short* __restrict__ Hres, unsigned short* __restrict__ Vres)
{
  __shared__ unsigned short KsL[2][4096];   // slabs: ko(16) x m(32) x 16B
  __shared__ unsigned short VtL[2][4096];   // dt(4) x o(4) x d'(32) x 16B
  __shared__ int   MsL[1024];
  __shared__ float RbL[128 * 32];           // [q_block 128][m 32]
  __shared__ float DbL[128 * 32];
  __shared__ float SsL[4][32 * 18];         // per-wave slab: S-transpose, then P

  const int tid  = threadIdx.x;
  const int w    = tid >> 6;
  const int lane = tid & 63;
  const int l32  = lane & 31;
  const int hi   = lane >> 5;

  const int bh = blockIdx.y;
  const int b  = bh >> 4;
  const int h  = bh & 15;
  const int q0 = blockIdx.x * 128 + w * 32;

  // ---- Q fragments: 8 k-steps x 8 bf16 ----
  s16x8 qf[8];
  {
    const unsigned short* qp = Qg + ((size_t)(b * 1024 + q0 + l32)) * 2048 + h * 128 + hi * 8;
#pragma unroll
    for (int ks = 0; ks < 8; ++ks) qf[ks] = *(const s16x8*)(qp + ks * 16);
  }

  f32x16 acc[4];        // O[q = l32][d = dt*32 + (r&3)+8*(r>>2)+4*hi]
  float m_run = -INFINITY, l_run = 0.f;   // per-lane (q = l32, m-half = hi)
#pragma unroll
  for (int dt = 0; dt < 4; ++dt)
#pragma unroll
    for (int r = 0; r < 16; ++r) acc[dt][r] = 0.f;

  // ---- DMA one tile of K/V: 4 instr/wave, slab-transposed placement ----
  auto issue_kv = [&](int t, int bf) {
    const int m0 = t * 32;
#pragma unroll
    for (int jj = 0; jj < 2; ++jj) {
      const int i = w * 2 + jj;
      gload_lds16(Kg + ((size_t)(b * 1024 + m0 + l32)) * 2048 + h * 128 + (2 * i + hi) * 8,
                  &KsL[bf][i * 512]);
      gload_lds16(Vtg + ((size_t)(bh * 128 + (i >> 1) * 32 + l32)) * 1024 + m0 + ((i & 1) * 2 + hi) * 8,
                  &VtL[bf][i * 512]);
    }
  };

  // ---- DMA one tile of bias into this wave's private slab ----
  auto issue_bias = [&](int t) {
    const int m0 = t * 32;
#pragma unroll
    for (int i = 0; i < 4; ++i) {
      const int qq = q0 + i * 8 + (lane >> 3);
      const int ch = (lane & 7) * 4;
      gload_lds16(rbf + ((size_t)bh * 1024 + qq) * 1024 + m0 + ch, &RbL[w * 1024 + i * 256]);
      gload_lds16(Dm  + ((size_t)b  * 1024 + qq) * 1024 + m0 + ch, &DbL[w * 1024 + i * 256]);
    }
  };

  gload_lds16(msk + b * 1024 + w * 256 + lane * 4, &MsL[w * 256]);
  issue_kv(0, 0);
  issue_bias(0);

#pragma unroll 1
  for (int t = 0; t < 32; ++t) {
    const int bf = t & 1;
    const int m0 = t * 32;

    asm volatile("s_waitcnt vmcnt(0)" ::: "memory");
    __builtin_amdgcn_s_barrier();

    if (t < 31) issue_kv(t + 1, bf ^ 1);
    __builtin_amdgcn_sched_barrier(0);

    // ---- QK: 8 MFMA 32x32x16 (sf: rows q in regs, col m = l32) ----
    f32x16 sf;
#pragma unroll
    for (int r = 0; r < 16; ++r) sf[r] = 0.f;
    __builtin_amdgcn_s_setprio(1);
#pragma unroll
    for (int ks = 0; ks < 8; ++ks) {
      const s16x8 kf = *(const s16x8*)&KsL[bf][(ks * 2 + hi) * 256 + l32 * 8];
      sf = __builtin_amdgcn_mfma_f32_32x32x16_bf16(qf[ks], kf, sf, 0, 0, 0);
    }
    __builtin_amdgcn_s_setprio(0);

    // ---- bias from LDS (conflict-free) + mask ----
    const bool on = MsL[m0 + l32] != 0;
    float sv[16];
#pragma unroll
    for (int r = 0; r < 16; ++r) {
      const int ql = (r & 3) + 8 * (r >> 2) + 4 * hi;
      const float bb = RbL[w * 1024 + ql * 32 + l32] + DbL[w * 1024 + ql * 32 + l32];
      sv[r] = on ? fmaf(sf[r], FACTOR, bb) : -INFINITY;
    }
    // bias(t) fully consumed -> stage bias(t+1)
    asm volatile("s_waitcnt lgkmcnt(0)" ::: "memory");
    __builtin_amdgcn_sched_barrier(0);
    if (t < 31) issue_bias(t + 1);
    __builtin_amdgcn_sched_barrier(0);

    // ---- transpose S through per-wave slab (2 phases, pitch 18) ----
    float s[16];
    if (l32 < 16) {
#pragma unroll
      for (int r = 0; r < 16; ++r) {
        const int ql = (r & 3) + 8 * (r >> 2) + 4 * hi;
        SsL[w][ql * 18 + l32] = sv[r];
      }
    }
    asm volatile("s_waitcnt lgkmcnt(0)" ::: "memory");
    __builtin_amdgcn_sched_barrier(0);
    if (hi == 0) {
#pragma unroll
      for (int j = 0; j < 16; ++j) s[j] = SsL[w][l32 * 18 + j];
    }
    __builtin_amdgcn_sched_barrier(0);
    if (l32 >= 16) {
#pragma unroll
      for (int r = 0; r < 16; ++r) {
        const int ql = (r & 3) + 8 * (r >> 2) + 4 * hi;
        SsL[w][ql * 18 + (l32 - 16)] = sv[r];
      }
    }
    asm volatile("s_waitcnt lgkmcnt(0)" ::: "memory");
    __builtin_amdgcn_sched_barrier(0);
    if (hi == 1) {
#pragma unroll
      for (int j = 0; j < 16; ++j) s[j] = SsL[w][l32 * 18 + j];
    }
    __builtin_amdgcn_sched_barrier(0);
    // lane (q=l32, hi) holds S[q][m0 + hi*16 + j] in s[j]

    // ---- per-lane online softmax (cross-half via shfl_xor 32) ----
    float mx = s[0];
#pragma unroll
    for (int j = 1; j < 16; ++j) mx = fmaxf(mx, s[j]);
    const float tmax = fmaxf(mx, __shfl_xor(mx, 32));

    const bool ok = (tmax <= m_run + 8.f);
    if (!__all(ok ? 1 : 0)) {
      const float mn = fmaxf(m_run, tmax);
      const float sc = (mn == m_run) ? 1.f : __expf(m_run - mn);
      m_run = mn;
      l_run *= sc;
#pragma unroll
      for (int dt = 0; dt < 4; ++dt)
#pragma unroll
        for (int r = 0; r < 16; ++r) acc[dt][r] *= sc;
    }

    float psv[16];
    float rs = 0.f;
#pragma unroll
    for (int j = 0; j < 16; ++j) {
      psv[j] = (s[j] == -INFINITY) ? 0.f : __expf(s[j] - m_run);
      rs += psv[j];
    }
    l_run += rs;

    // ---- P -> LDS (same slab, bf16 [q][m] pitch 36 shorts), read b128 ----
    {
      u32* Pw = (u32*)&SsL[w][0];
#pragma unroll
      for (int j = 0; j < 8; ++j) {
        const u32 word = (u32)f2bf(psv[2 * j]) | ((u32)f2bf(psv[2 * j + 1]) << 16);
        Pw[l32 * 18 + hi * 8 + j] = word;
      }
    }
    asm volatile("s_waitcnt lgkmcnt(0)" ::: "memory");
    __builtin_amdgcn_sched_barrier(0);

    const unsigned short* Pr = (const unsigned short*)&SsL[w][0];
    const s16x8 pf0 = *(const s16x8*)&Pr[l32 * 36 + hi * 8];
    const s16x8 pf1 = *(const s16x8*)&Pr[l32 * 36 + 16 + hi * 8];

    // ---- PV: operand-swapped mfma(A=V, B=P) -> D cols = q ----
    __builtin_amdgcn_s_setprio(1);
#pragma unroll
    for (int dt = 0; dt < 4; ++dt) {
      const s16x8 vf0 = *(const s16x8*)&VtL[bf][dt * 1024 + hi * 256 + l32 * 8];
      const s16x8 vf1 = *(const s16x8*)&VtL[bf][dt * 1024 + (2 + hi) * 256 + l32 * 8];
      acc[dt] = __builtin_amdgcn_mfma_f32_32x32x16_bf16(vf0, pf0, acc[dt], 0, 0, 0);
      acc[dt] = __builtin_amdgcn_mfma_f32_32x32x16_bf16(vf1, pf1, acc[dt], 0, 0, 0);
    }
    __builtin_amdgcn_s_setprio(0);
  }

  // ---- epilogue: combine l halves, normalize, bf16 scattered-d writes ----
  const float lt = l_run + __shfl_xor(l_run, 32);
  const float inv = (lt > 0.f) ? 1.f / lt : 0.f;

  const int q = q0 + l32;
#pragma unroll
  for (int dt = 0; dt < 4; ++dt) {
#pragma unroll
    for (int r = 0; r < 16; ++r) {
      const int dloc = (r & 3) + 8 * (r >> 2) + 4 * hi;
      const unsigned short o = f2bf(acc[dt][r] * inv);
      if (dt == 0) {
        Hres[((size_t)(b * 1024 + q)) * 512 + h * 32 + dloc] = o;
      } else {
        Vres[(((size_t)(b * 1024 + q)) * 3 + (dt - 1)) * 512 + h * 32 + dloc] = o;
      }
    }
  }
}

// ---------------------------------------------------------------------------
extern "C" void kernel_launch(void* const* d_in, const int* in_sizes, int n_in,
                              void* d_out, int out_size, void* d_ws, size_t ws_size,
                              hipStream_t stream)
{
  const float* Hp  = (const float*)d_in[0];
  const float* Vp  = (const float*)d_in[1];
  const float* Db  = (const float*)d_in[2];
  const float* rbf = (const float*)d_in[3];
  const int*   Hm  = (const int*)d_in[4];
  const float* Wq  = (const float*)d_in[5];
  const float* bq  = (const float*)d_in[6];
  const float* Wk  = (const float*)d_in[7];
  const float* bk  = (const float*)d_in[8];
  const float* Wv  = (const float*)d_in[9];
  const float* bv  = (const float*)d_in[10];
  const float* Wvv = (const float*)d_in[11];
  const float* Wo  = (const float*)d_in[12];
  const float* bo  = (const float*)d_in[13];
  const float* Wvo = (const float*)d_in[14];
  float* out = (float*)d_out;

  // ws layout (bytes):
  // Qb 16M | Kb 16M | Vt 16M | HresB 4M | VresB 12M | Hb 4M | Vpb 12M |
  // Wqb 2M | Wkb 2M | Wvb .5M | Wvvb .5M | Wob .5M | Wvob .5M  = ~86MB
  if (ws_size < (size_t)90177536) return;
  unsigned short* Qb    = (unsigned short*)d_ws;
  unsigned short* Kb    = Qb + 8388608;
  unsigned short* Vt    = Kb + 8388608;
  unsigned short* HresB = Vt + 8388608;
  unsigned short* VresB = HresB + 2097152;
  unsigned short* Hb    = VresB + 6291456;
  unsigned short* Vpb   = Hb + 2097152;
  unsigned short* Wqb   = Vpb + 6291456;
  unsigned short* Wkb   = Wqb + 1048576;
  unsigned short* Wvb   = Wkb + 1048576;
  unsigned short* Wvvb  = Wvb + 262144;
  unsigned short* Wob   = Wvvb + 262144;
  unsigned short* Wvob  = Wob + 262144;

  const dim3 blk(256);

  // one-time f32 -> bf16 conversions
  cvt_bf16<<<dim3(1024), blk, 0, stream>>>(Hp,  Hb,   2097152);
  cvt_bf16<<<dim3(3072), blk, 0, stream>>>(Vp,  Vpb,  6291456);
  cvt_bf16<<<dim3(512),  blk, 0, stream>>>(Wq,  Wqb,  1048576);
  cvt_bf16<<<dim3(512),  blk, 0, stream>>>(Wk,  Wkb,  1048576);
  cvt_bf16<<<dim3(128),  blk, 0, stream>>>(Wv,  Wvb,  262144);
  cvt_bf16<<<dim3(128),  blk, 0, stream>>>(Wvv, Wvvb, 262144);
  cvt_bf16<<<dim3(128),  blk, 0, stream>>>(Wo,  Wob,  262144);
  cvt_bf16<<<dim3(128),  blk, 0, stream>>>(Wvo, Wvob, 262144);

  // projections (bf16 in, DMA-staged)
  gemm_bf<<<dim3(32, 16), blk, 0, stream>>>(Hb, Wqb, bq, Qb, 4096, 2048, 512, 3);
  gemm_bf<<<dim3(32, 16), blk, 0, stream>>>(Hb, Wkb, bk, Kb, 4096, 2048, 512, 3);
  gemm_bf<<<dim3(4, 32),  blk, 0, stream>>>(Wvb, Hb, bv, Vt, 512, 4096, 512, 4);
  gemm_bf<<<dim3(4, 96),  blk, 0, stream>>>(Wvvb, Vpb, nullptr, Vt, 512, 12288, 512, 5);

  attn_mfma<<<dim3(8, 64), blk, 0, stream>>>(Qb, Kb, Vt, rbf, Db, Hm, HresB, VresB);

  // output projections
  gemm_bf<<<dim3(32, 4), blk, 0, stream>>>(HresB, Wob, bo, out, 4096, 512, 512, 0);
  gemm_bf<<<dim3(96, 4), blk, 0, stream>>>(VresB, Wvob, nullptr, out + 2097152, 12288, 512, 512, 0);
}

// Round 18
// 283.920 us; speedup vs baseline: 1.0836x; 1.0836x over previous
//
#include <hip/hip_runtime.h>
#include <cmath>

#define FACTOR 0.08838834764831845f

typedef short s16x8 __attribute__((ext_vector_type(8)));
typedef float f32x4 __attribute__((ext_vector_type(4)));
typedef float f32x16 __attribute__((ext_vector_type(16)));
typedef unsigned int u32;

__device__ __forceinline__ unsigned short f2bf(float x) {
  unsigned int u = __float_as_uint(x);
  u += 0x7FFFu + ((u >> 16) & 1u);
  return (unsigned short)(u >> 16);
}

__device__ __forceinline__ s16x8 pack8(float4 a, float4 b) {
  s16x8 r;
  r[0] = (short)f2bf(a.x); r[1] = (short)f2bf(a.y);
  r[2] = (short)f2bf(a.z); r[3] = (short)f2bf(a.w);
  r[4] = (short)f2bf(b.x); r[5] = (short)f2bf(b.y);
  r[6] = (short)f2bf(b.z); r[7] = (short)f2bf(b.w);
  return r;
}

__device__ __forceinline__ void gload_lds16(const void* g, void* l) {
  __builtin_amdgcn_global_load_lds(
      (const __attribute__((address_space(1))) u32*)g,
      (__attribute__((address_space(3))) u32*)l, 16, 0, 0);
}

// ---------------------------------------------------------------------------
// Fused f32 -> bf16 conversion of all 8 tensors (one launch).
// Block ranges (2048 elems/block): Hb 1024 | Vpb 3072 | Wq 512 | Wk 512 |
// Wv 128 | Wvv 128 | Wo 128 | Wvo 128   (total 5632 blocks)
// ---------------------------------------------------------------------------
__global__ __launch_bounds__(256) void cvt_all(
    const float* __restrict__ Hp,  unsigned short* __restrict__ Hb,
    const float* __restrict__ Vp,  unsigned short* __restrict__ Vpb,
    const float* __restrict__ Wq,  unsigned short* __restrict__ Wqb,
    const float* __restrict__ Wk,  unsigned short* __restrict__ Wkb,
    const float* __restrict__ Wv,  unsigned short* __restrict__ Wvb,
    const float* __restrict__ Wvv, unsigned short* __restrict__ Wvvb,
    const float* __restrict__ Wo,  unsigned short* __restrict__ Wob,
    const float* __restrict__ Wvo, unsigned short* __restrict__ Wvob)
{
  int blk = blockIdx.x;
  const float* src; unsigned short* dst;
  if      (blk < 1024) { src = Hp;  dst = Hb; }
  else if (blk < 4096) { src = Vp;  dst = Vpb;  blk -= 1024; }
  else if (blk < 4608) { src = Wq;  dst = Wqb;  blk -= 4096; }
  else if (blk < 5120) { src = Wk;  dst = Wkb;  blk -= 4608; }
  else if (blk < 5248) { src = Wv;  dst = Wvb;  blk -= 5120; }
  else if (blk < 5376) { src = Wvv; dst = Wvvb; blk -= 5248; }
  else if (blk < 5504) { src = Wo;  dst = Wob;  blk -= 5376; }
  else                 { src = Wvo; dst = Wvob; blk -= 5504; }
  const int i = (blk * 256 + threadIdx.x) * 8;
  const float4 a = *(const float4*)(src + i);
  const float4 b = *(const float4*)(src + i + 4);
  *(s16x8*)&dst[i] = pack8(a, b);
}

// ---------------------------------------------------------------------------
// bf16 MFMA GEMM, DMA-staged + DOUBLE-BUFFERED (attn-style pipeline):
// prologue issues tile 0; loop = vmcnt(0) / barrier / issue(t+1) / compute(t).
// ko-slab LDS (8 slabs x 1040 shorts, 16-short pad -> conflict-free b128).
// 128x128 tile, 4 waves (2x2), BK=64.
// mode 0: f32 C | mode 3: bf16 C | mode 4/5: Vt scatters (5 = fused V remap)
// ---------------------------------------------------------------------------
__global__ __launch_bounds__(256, 2) void gemm_bf(
    const unsigned short* __restrict__ A, const unsigned short* __restrict__ B,
    const float* __restrict__ bias, void* __restrict__ C,
    int M, int N, int K, int mode)
{
  __shared__ unsigned short ASl[2][8 * 1040];
  __shared__ unsigned short BSl[2][8 * 1040];

  const int tid = threadIdx.x;
  const int w = tid >> 6, lane = tid & 63;
  const int l16 = lane & 15, lg = lane >> 4;
  const int wm = w >> 1, wn = w & 1;
  const int m0 = blockIdx.x * 128;
  const int n0 = blockIdx.y * 128;

  f32x4 acc[4][4];
#pragma unroll
  for (int mt = 0; mt < 4; ++mt)
#pragma unroll
    for (int nt = 0; nt < 4; ++nt)
#pragma unroll
      for (int r = 0; r < 4; ++r) acc[mt][nt][r] = 0.f;

  auto issue = [&](int k0, int bf) {
#pragma unroll
    for (int i = 0; i < 4; ++i) {
      const int u = i * 256 + tid;           // unit: 16B, ko-major
      const int row = u & 127, ko = u >> 7;
      const int dst = ko * 1040 + row * 8;
      gload_lds16(A + (size_t)(m0 + row) * K + k0 + ko * 8, &ASl[bf][dst]);
      const unsigned short* bp;
      if (mode == 5) {
        const int t = n0 + row;
        const int q3 = t >> 10, n = t & 1023;
        const int bb = q3 / 3, cd = q3 - 3 * bb;
        bp = B + (((size_t)(bb * 1024 + n)) * 3 + cd) * 512 + k0 + ko * 8;
      } else {
        bp = B + (size_t)(n0 + row) * K + k0 + ko * 8;
      }
      gload_lds16(bp, &BSl[bf][dst]);
    }
  };

  issue(0, 0);

  const int NT = K >> 6;
#pragma unroll 1
  for (int t = 0; t < NT; ++t) {
    const int bf = t & 1;
    asm volatile("s_waitcnt vmcnt(0)" ::: "memory");   // tile t's DMAs landed
    __builtin_amdgcn_s_barrier();                      // all waves done (also
                                                       // guards buf^1 reuse)
    if (t + 1 < NT) issue((t + 1) << 6, bf ^ 1);
    __builtin_amdgcn_sched_barrier(0);

#pragma unroll
    for (int ks = 0; ks < 2; ++ks) {
      s16x8 af[4], bfr[4];
#pragma unroll
      for (int mt = 0; mt < 4; ++mt)
        af[mt] = *(const s16x8*)&ASl[bf][(ks * 4 + lg) * 1040 + (wm * 64 + mt * 16 + l16) * 8];
#pragma unroll
      for (int nt = 0; nt < 4; ++nt)
        bfr[nt] = *(const s16x8*)&BSl[bf][(ks * 4 + lg) * 1040 + (wn * 64 + nt * 16 + l16) * 8];
#pragma unroll
      for (int mt = 0; mt < 4; ++mt)
#pragma unroll
        for (int nt = 0; nt < 4; ++nt)
          acc[mt][nt] = __builtin_amdgcn_mfma_f32_16x16x32_bf16(af[mt], bfr[nt], acc[mt][nt], 0, 0, 0);
    }
  }

  const int rbase = m0 + wm * 64;
  const int cbase = n0 + wn * 64;

  if (mode == 0 || mode == 3) {
#pragma unroll
    for (int nt = 0; nt < 4; ++nt) {
      const int c = cbase + nt * 16 + l16;
      const float bb = bias ? bias[c] : 0.f;
#pragma unroll
      for (int mt = 0; mt < 4; ++mt) {
#pragma unroll
        for (int r = 0; r < 4; ++r) {
          const int row = rbase + mt * 16 + lg * 4 + r;
          const float v = acc[mt][nt][r] + bb;
          if (mode == 0) ((float*)C)[(size_t)row * N + c] = v;
          else           ((unsigned short*)C)[(size_t)row * N + c] = f2bf(v);
        }
      }
    }
  } else {
    unsigned short* Cb = (unsigned short*)C;
#pragma unroll
    for (int mt = 0; mt < 4; ++mt) {
#pragma unroll
      for (int r = 0; r < 4; ++r) {
        const int ch = rbase + mt * 16 + lg * 4 + r;
        const float bb = bias ? bias[ch] : 0.f;
        const int h = ch >> 5, dq = ch & 31;
#pragma unroll
        for (int nt = 0; nt < 4; ++nt) {
          const int t = cbase + nt * 16 + l16;
          size_t off;
          if (mode == 4) {
            const int b = t >> 10, n = t & 1023;
            off = (((size_t)(b * 16 + h)) * 128 + dq) * 1024 + n;
          } else {
            const int q3 = t >> 10, n = t & 1023;
            const int b = q3 / 3, cd = q3 - 3 * b;
            off = (((size_t)(b * 16 + h)) * 128 + 32 + cd * 32 + dq) * 1024 + n;
          }
          Cb[off] = f2bf(acc[mt][nt][r] + bb);
        }
      }
    }
  }
}

// ---------------------------------------------------------------------------
// Flash attention (R16/R17-passing structure, bf16 Hres/Vres outputs).
// ---------------------------------------------------------------------------
__global__ __launch_bounds__(256, 2) void attn_mfma(
    const unsigned short* __restrict__ Qg, const unsigned short* __restrict__ Kg,
    const unsigned short* __restrict__ Vtg, const float* __restrict__ rbf,
    const float* __restrict__ Dm, const int* __restrict__ msk,
    unsigned short* __restrict__ Hres, unsigned short* __restrict__ Vres)
{
  __shared__ unsigned short KsL[2][4096];   // slabs: ko(16) x m(32) x 16B
  __shared__ unsigned short VtL[2][4096];   // dt(4) x o(4) x d'(32) x 16B
  __shared__ int   MsL[1024];
  __shared__ float RbL[128 * 32];           // [q_block 128][m 32]
  __shared__ float DbL[128 * 32];
  __shared__ float SsL[4][32 * 18];         // per-wave slab: S-transpose, then P

  const int tid  = threadIdx.x;
  const int w    = tid >> 6;
  const int lane = tid & 63;
  const int l32  = lane & 31;
  const int hi   = lane >> 5;

  const int bh = blockIdx.y;
  const int b  = bh >> 4;
  const int h  = bh & 15;
  const int q0 = blockIdx.x * 128 + w * 32;

  s16x8 qf[8];
  {
    const unsigned short* qp = Qg + ((size_t)(b * 1024 + q0 + l32)) * 2048 + h * 128 + hi * 8;
#pragma unroll
    for (int ks = 0; ks < 8; ++ks) qf[ks] = *(const s16x8*)(qp + ks * 16);
  }

  f32x16 acc[4];        // O[q = l32][d = dt*32 + (r&3)+8*(r>>2)+4*hi]
  float m_run = -INFINITY, l_run = 0.f;
#pragma unroll
  for (int dt = 0; dt < 4; ++dt)
#pragma unroll
    for (int r = 0; r < 16; ++r) acc[dt][r] = 0.f;

  auto issue_kv = [&](int t, int bf) {
    const int m0 = t * 32;
#pragma unroll
    for (int jj = 0; jj < 2; ++jj) {
      const int i = w * 2 + jj;
      gload_lds16(Kg + ((size_t)(b * 1024 + m0 + l32)) * 2048 + h * 128 + (2 * i + hi) * 8,
                  &KsL[bf][i * 512]);
      gload_lds16(Vtg + ((size_t)(bh * 128 + (i >> 1) * 32 + l32)) * 1024 + m0 + ((i & 1) * 2 + hi) * 8,
                  &VtL[bf][i * 512]);
    }
  };

  auto issue_bias = [&](int t) {
    const int m0 = t * 32;
#pragma unroll
    for (int i = 0; i < 4; ++i) {
      const int qq = q0 + i * 8 + (lane >> 3);
      const int ch = (lane & 7) * 4;
      gload_lds16(rbf + ((size_t)bh * 1024 + qq) * 1024 + m0 + ch, &RbL[w * 1024 + i * 256]);
      gload_lds16(Dm  + ((size_t)b  * 1024 + qq) * 1024 + m0 + ch, &DbL[w * 1024 + i * 256]);
    }
  };

  gload_lds16(msk + b * 1024 + w * 256 + lane * 4, &MsL[w * 256]);
  issue_kv(0, 0);
  issue_bias(0);

#pragma unroll 1
  for (int t = 0; t < 32; ++t) {
    const int bf = t & 1;
    const int m0 = t * 32;

    asm volatile("s_waitcnt vmcnt(0)" ::: "memory");
    __builtin_amdgcn_s_barrier();

    if (t < 31) issue_kv(t + 1, bf ^ 1);
    __builtin_amdgcn_sched_barrier(0);

    // ---- QK: 8 MFMA 32x32x16 ----
    f32x16 sf;
#pragma unroll
    for (int r = 0; r < 16; ++r) sf[r] = 0.f;
    __builtin_amdgcn_s_setprio(1);
#pragma unroll
    for (int ks = 0; ks < 8; ++ks) {
      const s16x8 kf = *(const s16x8*)&KsL[bf][(ks * 2 + hi) * 256 + l32 * 8];
      sf = __builtin_amdgcn_mfma_f32_32x32x16_bf16(qf[ks], kf, sf, 0, 0, 0);
    }
    __builtin_amdgcn_s_setprio(0);

    // ---- bias from LDS + mask ----
    const bool on = MsL[m0 + l32] != 0;
    float sv[16];
#pragma unroll
    for (int r = 0; r < 16; ++r) {
      const int ql = (r & 3) + 8 * (r >> 2) + 4 * hi;
      const float bb = RbL[w * 1024 + ql * 32 + l32] + DbL[w * 1024 + ql * 32 + l32];
      sv[r] = on ? fmaf(sf[r], FACTOR, bb) : -INFINITY;
    }
    asm volatile("s_waitcnt lgkmcnt(0)" ::: "memory");
    __builtin_amdgcn_sched_barrier(0);
    if (t < 31) issue_bias(t + 1);
    __builtin_amdgcn_sched_barrier(0);

    // ---- transpose S through per-wave slab (2 phases, pitch 18) ----
    float s[16];
    if (l32 < 16) {
#pragma unroll
      for (int r = 0; r < 16; ++r) {
        const int ql = (r & 3) + 8 * (r >> 2) + 4 * hi;
        SsL[w][ql * 18 + l32] = sv[r];
      }
    }
    asm volatile("s_waitcnt lgkmcnt(0)" ::: "memory");
    __builtin_amdgcn_sched_barrier(0);
    if (hi == 0) {
#pragma unroll
      for (int j = 0; j < 16; ++j) s[j] = SsL[w][l32 * 18 + j];
    }
    __builtin_amdgcn_sched_barrier(0);
    if (l32 >= 16) {
#pragma unroll
      for (int r = 0; r < 16; ++r) {
        const int ql = (r & 3) + 8 * (r >> 2) + 4 * hi;
        SsL[w][ql * 18 + (l32 - 16)] = sv[r];
      }
    }
    asm volatile("s_waitcnt lgkmcnt(0)" ::: "memory");
    __builtin_amdgcn_sched_barrier(0);
    if (hi == 1) {
#pragma unroll
      for (int j = 0; j < 16; ++j) s[j] = SsL[w][l32 * 18 + j];
    }
    __builtin_amdgcn_sched_barrier(0);

    // ---- per-lane online softmax ----
    float mx = s[0];
#pragma unroll
    for (int j = 1; j < 16; ++j) mx = fmaxf(mx, s[j]);
    const float tmax = fmaxf(mx, __shfl_xor(mx, 32));

    const bool ok = (tmax <= m_run + 8.f);
    if (!__all(ok ? 1 : 0)) {
      const float mn = fmaxf(m_run, tmax);
      const float sc = (mn == m_run) ? 1.f : __expf(m_run - mn);
      m_run = mn;
      l_run *= sc;
#pragma unroll
      for (int dt = 0; dt < 4; ++dt)
#pragma unroll
        for (int r = 0; r < 16; ++r) acc[dt][r] *= sc;
    }

    float psv[16];
    float rs = 0.f;
#pragma unroll
    for (int j = 0; j < 16; ++j) {
      psv[j] = (s[j] == -INFINITY) ? 0.f : __expf(s[j] - m_run);
      rs += psv[j];
    }
    l_run += rs;

    // ---- P -> LDS (same slab), read b128 ----
    {
      u32* Pw = (u32*)&SsL[w][0];
#pragma unroll
      for (int j = 0; j < 8; ++j) {
        const u32 word = (u32)f2bf(psv[2 * j]) | ((u32)f2bf(psv[2 * j + 1]) << 16);
        Pw[l32 * 18 + hi * 8 + j] = word;
      }
    }
    asm volatile("s_waitcnt lgkmcnt(0)" ::: "memory");
    __builtin_amdgcn_sched_barrier(0);

    const unsigned short* Pr = (const unsigned short*)&SsL[w][0];
    const s16x8 pf0 = *(const s16x8*)&Pr[l32 * 36 + hi * 8];
    const s16x8 pf1 = *(const s16x8*)&Pr[l32 * 36 + 16 + hi * 8];

    // ---- PV: operand-swapped mfma(A=V, B=P) ----
    __builtin_amdgcn_s_setprio(1);
#pragma unroll
    for (int dt = 0; dt < 4; ++dt) {
      const s16x8 vf0 = *(const s16x8*)&VtL[bf][dt * 1024 + hi * 256 + l32 * 8];
      const s16x8 vf1 = *(const s16x8*)&VtL[bf][dt * 1024 + (2 + hi) * 256 + l32 * 8];
      acc[dt] = __builtin_amdgcn_mfma_f32_32x32x16_bf16(vf0, pf0, acc[dt], 0, 0, 0);
      acc[dt] = __builtin_amdgcn_mfma_f32_32x32x16_bf16(vf1, pf1, acc[dt], 0, 0, 0);
    }
    __builtin_amdgcn_s_setprio(0);
  }

  // ---- epilogue ----
  const float lt = l_run + __shfl_xor(l_run, 32);
  const float inv = (lt > 0.f) ? 1.f / lt : 0.f;

  const int q = q0 + l32;
#pragma unroll
  for (int dt = 0; dt < 4; ++dt) {
#pragma unroll
    for (int r = 0; r < 16; ++r) {
      const int dloc = (r & 3) + 8 * (r >> 2) + 4 * hi;
      const unsigned short o = f2bf(acc[dt][r] * inv);
      if (dt == 0) {
        Hres[((size_t)(b * 1024 + q)) * 512 + h * 32 + dloc] = o;
      } else {
        Vres[(((size_t)(b * 1024 + q)) * 3 + (dt - 1)) * 512 + h * 32 + dloc] = o;
      }
    }
  }
}

// ---------------------------------------------------------------------------
extern "C" void kernel_launch(void* const* d_in, const int* in_sizes, int n_in,
                              void* d_out, int out_size, void* d_ws, size_t ws_size,
                              hipStream_t stream)
{
  const float* Hp  = (const float*)d_in[0];
  const float* Vp  = (const float*)d_in[1];
  const float* Db  = (const float*)d_in[2];
  const float* rbf = (const float*)d_in[3];
  const int*   Hm  = (const int*)d_in[4];
  const float* Wq  = (const float*)d_in[5];
  const float* bq  = (const float*)d_in[6];
  const float* Wk  = (const float*)d_in[7];
  const float* bk  = (const float*)d_in[8];
  const float* Wv  = (const float*)d_in[9];
  const float* bv  = (const float*)d_in[10];
  const float* Wvv = (const float*)d_in[11];
  const float* Wo  = (const float*)d_in[12];
  const float* bo  = (const float*)d_in[13];
  const float* Wvo = (const float*)d_in[14];
  float* out = (float*)d_out;

  if (ws_size < (size_t)90177536) return;
  unsigned short* Qb    = (unsigned short*)d_ws;
  unsigned short* Kb    = Qb + 8388608;
  unsigned short* Vt    = Kb + 8388608;
  unsigned short* HresB = Vt + 8388608;
  unsigned short* VresB = HresB + 2097152;
  unsigned short* Hb    = VresB + 6291456;
  unsigned short* Vpb   = Hb + 2097152;
  unsigned short* Wqb   = Vpb + 6291456;
  unsigned short* Wkb   = Wqb + 1048576;
  unsigned short* Wvb   = Wkb + 1048576;
  unsigned short* Wvvb  = Wvb + 262144;
  unsigned short* Wob   = Wvvb + 262144;
  unsigned short* Wvob  = Wob + 262144;

  const dim3 blk(256);

  cvt_all<<<dim3(5632), blk, 0, stream>>>(Hp, Hb, Vp, Vpb, Wq, Wqb, Wk, Wkb,
                                          Wv, Wvb, Wvv, Wvvb, Wo, Wob, Wvo, Wvob);

  gemm_bf<<<dim3(32, 16), blk, 0, stream>>>(Hb, Wqb, bq, Qb, 4096, 2048, 512, 3);
  gemm_bf<<<dim3(32, 16), blk, 0, stream>>>(Hb, Wkb, bk, Kb, 4096, 2048, 512, 3);
  gemm_bf<<<dim3(4, 32),  blk, 0, stream>>>(Wvb, Hb, bv, Vt, 512, 4096, 512, 4);
  gemm_bf<<<dim3(4, 96),  blk, 0, stream>>>(Wvvb, Vpb, nullptr, Vt, 512, 12288, 512, 5);

  attn_mfma<<<dim3(8, 64), blk, 0, stream>>>(Qb, Kb, Vt, rbf, Db, Hm, HresB, VresB);

  gemm_bf<<<dim3(32, 4), blk, 0, stream>>>(HresB, Wob, bo, out, 4096, 512, 512, 0);
  gemm_bf<<<dim3(96, 4), blk, 0, stream>>>(VresB, Wvob, nullptr, out + 2097152, 12288, 512, 512, 0);
}